// Round 1
// 407.766 us; speedup vs baseline: 1.0122x; 1.0122x over previous
//
#include <hip/hip_runtime.h>
#include <stdint.h>

#define M_DIM 8192
#define N_DIM 4096
#define K_DIM 4096
#define BM 256
#define BN 256
#define BKS 64                    // K-slab bytes (i8) per pipeline stage
#define NSLAB (K_DIM / BKS)       // 64 slabs
#define SLOT_BYTES (256 * BKS)    // 16 KB per matrix per ring slot

typedef int i32x4 __attribute__((ext_vector_type(4)));

__device__ __forceinline__ void async_copy16(const void* g, void* l) {
    __builtin_amdgcn_global_load_lds(
        (const __attribute__((address_space(1))) void*)g,
        (__attribute__((address_space(3))) void*)l, 16, 0, 0);
}

// ---- pass 1: per-block partial sums of |w| (deterministic, no atomics) ----
__global__ __launch_bounds__(256) void abssum_partial(const float4* __restrict__ w,
                                                      double* __restrict__ partials) {
    const int lane = threadIdx.x & 63;
    const int wave = threadIdx.x >> 6;
    int base = blockIdx.x * 4096 + threadIdx.x;
    float s = 0.f;
    #pragma unroll
    for (int i = 0; i < 16; i++) {
        float4 v = w[base + i * 256];
        s += fabsf(v.x) + fabsf(v.y) + fabsf(v.z) + fabsf(v.w);
    }
    double d = (double)s;
    #pragma unroll
    for (int off = 32; off > 0; off >>= 1) d += __shfl_down(d, off, 64);
    __shared__ double wsum[4];
    if (lane == 0) wsum[wave] = d;
    __syncthreads();
    if (threadIdx.x == 0)
        partials[blockIdx.x] = (wsum[0] + wsum[1]) + (wsum[2] + wsum[3]);
}

// ---- pass 2: reduce 1024 partials -> gamma ----
__global__ __launch_bounds__(256) void gamma_reduce(const double* __restrict__ partials,
                                                    float* __restrict__ gamma_out) {
    const int lane = threadIdx.x & 63;
    const int wave = threadIdx.x >> 6;
    double d = partials[threadIdx.x] + partials[threadIdx.x + 256] +
               partials[threadIdx.x + 512] + partials[threadIdx.x + 768];
    #pragma unroll
    for (int off = 32; off > 0; off >>= 1) d += __shfl_down(d, off, 64);
    __shared__ double wsum[4];
    if (lane == 0) wsum[wave] = d;
    __syncthreads();
    if (threadIdx.x == 0) {
        double total = (wsum[0] + wsum[1]) + (wsum[2] + wsum[3]);
        float g = (float)(total * (1.0 / 16777216.0));  // mean |w|
        gamma_out[0] = fmaxf(g, 1e-8f);
    }
}

// ---- pass 3: quantize weight to ternary i8 ----
__global__ __launch_bounds__(256) void wquant(const float4* __restrict__ w,
                                              char4* __restrict__ qw,
                                              const float* __restrict__ gamma_p, int n4) {
    float gamma = gamma_p[0];
    int i = blockIdx.x * blockDim.x + threadIdx.x;
    if (i >= n4) return;
    float4 v = w[i];
    char4 o;
    o.x = (signed char)fminf(fmaxf(rintf(v.x / gamma), -1.f), 1.f);
    o.y = (signed char)fminf(fmaxf(rintf(v.y / gamma), -1.f), 1.f);
    o.z = (signed char)fminf(fmaxf(rintf(v.z / gamma), -1.f), 1.f);
    o.w = (signed char)fminf(fmaxf(rintf(v.w / gamma), -1.f), 1.f);
    qw[i] = o;
}

// ---- pass 4: per-row absmax + quantize x to i8 (register-resident) ----
__global__ __launch_bounds__(256) void xquant(const float4* __restrict__ x,
                                              char4* __restrict__ xq,
                                              float* __restrict__ xscale) {
    const int row = blockIdx.x;
    const int lane = threadIdx.x & 63;
    const int wave = threadIdx.x >> 6;
    const float4* xr = x + (size_t)row * (K_DIM / 4);
    float4 v[4];
    float m = 0.f;
    #pragma unroll
    for (int i = 0; i < 4; i++) {
        v[i] = xr[threadIdx.x + i * 256];
        m = fmaxf(m, fmaxf(fmaxf(fabsf(v[i].x), fabsf(v[i].y)),
                           fmaxf(fabsf(v[i].z), fabsf(v[i].w))));
    }
    #pragma unroll
    for (int off = 32; off > 0; off >>= 1) m = fmaxf(m, __shfl_down(m, off, 64));
    __shared__ float wmax[4];
    if (lane == 0) wmax[wave] = m;
    __syncthreads();
    const float mx = fmaxf(fmaxf(wmax[0], wmax[1]), fmaxf(wmax[2], wmax[3]));
    const float scale = fmaxf(mx * (1.f / 127.f), 1e-30f);
    const float inv = 1.f / scale;
    if (threadIdx.x == 0) xscale[row] = scale;
    char4* oq = xq + (size_t)row * (K_DIM / 4);
    #pragma unroll
    for (int i = 0; i < 4; i++) {
        char4 o;
        o.x = (signed char)fminf(fmaxf(rintf(v[i].x * inv), -127.f), 127.f);
        o.y = (signed char)fminf(fmaxf(rintf(v[i].y * inv), -127.f), 127.f);
        o.z = (signed char)fminf(fmaxf(rintf(v[i].z * inv), -127.f), 127.f);
        o.w = (signed char)fminf(fmaxf(rintf(v[i].w * inv), -127.f), 127.f);
        oq[threadIdx.x + i * 256] = o;
    }
}

// ---- pass 5: C[M,N] = scale[m] * (Xq[M,K] @ Qw[N,K]^T)_i32 + bias ----
//
// 256x256 tile, 8 waves (2M x 4N), each wave -> 128x64 output (8x4 frags of
// mfma_i32_16x16x64_i8). Deep pipeline: K split into 64 B slabs, ring of 4
// LDS slots per matrix (4 x 16 KB x 2 = 128 KB). Slab t+3 is staged with
// global_load_lds while slab t computes; per-slab boundary sync is a COUNTED
// s_waitcnt vmcnt(8) (2 slabs = 8 loads/thread in flight) + raw s_barrier --
// never a drain in the main loop (T3+T4). setprio(1) around each 16-MFMA
// cluster (T5).
//
// Invariants:
//  - slot(t) = t&3.  Staging slab t+3 writes slot (t-1)&3, whose last reader
//    finished at the slab t-1 boundary barrier -> WAR-safe.
//  - vmcnt(8) at the slab-t boundary retires everything except the loads of
//    slabs t+2, t+3 -> slab t+1 is resident before any wave reads it.
//  - Swizzle (both-sides involution): phys 16B-chunk p = c ^ ((row>>1)&3).
//    Implemented by permuting the per-lane GLOBAL source of global_load_lds
//    (LDS dest stays linear, as HW requires) and applying the same XOR on the
//    ds_read side. 16-lane read groups then cover all 8 bank-quads twice ->
//    2-way aliasing = conflict-free.
__global__ __launch_bounds__(512, 2) void gemm_kernel(
    const char* __restrict__ xq,       // [M,K] i8
    const char* __restrict__ qw,       // [N,K] i8 ternary
    const float* __restrict__ xscale,  // [M]
    const float* __restrict__ bias,    // [N]
    float* __restrict__ out)           // [M,N] fp32
{
    __shared__ __align__(16) char As[4][SLOT_BYTES];   // 64 KB
    __shared__ __align__(16) char Bs[4][SLOT_BYTES];   // 64 KB

    const int tid  = threadIdx.x;
    const int wave = tid >> 6;
    const int lane = tid & 63;
    const int wm   = (wave >> 2) * 128;   // 0 or 128
    const int wn   = (wave & 3) * 64;     // 0,64,128,192
    const int lm   = lane & 15;
    const int q4   = lane >> 4;           // logical 16B k-chunk 0..3

    const int bm = blockIdx.y * BM;
    const int bn = blockIdx.x * BN;

    // Staging: wave w covers rows [w*32, w*32+32) of A and of B, in two
    // 16-row rounds j=0,1 (one global_load_lds each: 64 lanes x 16 B = 1 KB).
    // Lane l -> row base + (l>>2), phys chunk l&3; source chunk = swizzle^-1.
    const int rsub = lane >> 2;                         // 0..15
    const int csw  = (lane & 3) ^ ((lane >> 3) & 3);    // (l&3) ^ ((row>>1)&3)
    const char* gA[2];
    const char* gB[2];
    int ldsOff[2];
    #pragma unroll
    for (int j = 0; j < 2; j++) {
        const int r = wave * 32 + j * 16 + rsub;
        gA[j] = xq + (size_t)(bm + r) * K_DIM + csw * 16;
        gB[j] = qw + (size_t)(bn + r) * K_DIM + csw * 16;
        ldsOff[j] = (wave * 32 + j * 16) * BKS;
    }

    i32x4 acc[8][4];
    #pragma unroll
    for (int i = 0; i < 8; i++)
        #pragma unroll
        for (int j = 0; j < 4; j++) acc[i][j] = (i32x4){0, 0, 0, 0};

    // read-side swizzled chunk offset: phys = q4 ^ ((row>>1)&3), row>>1&3 == lm>>1&3
    const int pc = (q4 ^ ((lm >> 1) & 3)) * 16;

    // ---- prologue: stage slabs 0,1,2 (12 loads/thread) ----
    #pragma unroll
    for (int s = 0; s < 3; s++) {
        #pragma unroll
        for (int j = 0; j < 2; j++) {
            async_copy16(gA[j] + s * BKS, &As[s][ldsOff[j]]);
            async_copy16(gB[j] + s * BKS, &Bs[s][ldsOff[j]]);
        }
    }
    asm volatile("s_waitcnt vmcnt(8)" ::: "memory");   // slab 0 resident
    __builtin_amdgcn_s_barrier();

    for (int t = 0; t < NSLAB; ++t) {
        const char* Ab = As[t & 3];
        const char* Bb = Bs[t & 3];
        const int  ts       = t + 3;
        const bool do_stage = ts < NSLAB;
        const int  slot     = ts & 3;

        // ================= phase 0: mi 0..3 =================
        i32x4 a[4], b[4];
        #pragma unroll
        for (int mi = 0; mi < 4; mi++)
            a[mi] = *(const i32x4*)(Ab + (wm + mi * 16 + lm) * BKS + pc);
        #pragma unroll
        for (int ni = 0; ni < 4; ni++)
            b[ni] = *(const i32x4*)(Bb + (wn + ni * 16 + lm) * BKS + pc);
        if (do_stage) {
            async_copy16(gA[0] + ts * BKS, &As[slot][ldsOff[0]]);
            async_copy16(gB[0] + ts * BKS, &Bs[slot][ldsOff[0]]);
        }
        __builtin_amdgcn_s_barrier();
        __builtin_amdgcn_s_setprio(1);
        #pragma unroll
        for (int mi = 0; mi < 4; mi++)
            #pragma unroll
            for (int ni = 0; ni < 4; ni++)
                acc[mi][ni] = __builtin_amdgcn_mfma_i32_16x16x64_i8(
                    a[mi], b[ni], acc[mi][ni], 0, 0, 0);
        __builtin_amdgcn_s_setprio(0);
        __builtin_amdgcn_s_barrier();

        // ================= phase 1: mi 4..7 =================
        i32x4 a2[4];
        #pragma unroll
        for (int mi = 0; mi < 4; mi++)
            a2[mi] = *(const i32x4*)(Ab + (wm + (4 + mi) * 16 + lm) * BKS + pc);
        if (do_stage) {
            async_copy16(gA[1] + ts * BKS, &As[slot][ldsOff[1]]);
            async_copy16(gB[1] + ts * BKS, &Bs[slot][ldsOff[1]]);
        }
        __builtin_amdgcn_s_barrier();
        __builtin_amdgcn_s_setprio(1);
        #pragma unroll
        for (int mi = 0; mi < 4; mi++)
            #pragma unroll
            for (int ni = 0; ni < 4; ni++)
                acc[4 + mi][ni] = __builtin_amdgcn_mfma_i32_16x16x64_i8(
                    a2[mi], b[ni], acc[4 + mi][ni], 0, 0, 0);
        __builtin_amdgcn_s_setprio(0);

        // ---- slab boundary: counted wait, raw barrier ----
        if (t < NSLAB - 3) {
            asm volatile("s_waitcnt vmcnt(8)" ::: "memory");
        } else if (t == NSLAB - 3) {
            asm volatile("s_waitcnt vmcnt(4)" ::: "memory");
        } else if (t == NSLAB - 2) {
            asm volatile("s_waitcnt vmcnt(0)" ::: "memory");
        }
        if (t < NSLAB - 1) __builtin_amdgcn_s_barrier();
    }

    // epilogue: C/D layout col=lane&15, row=quad*4+reg (shape-determined)
    float bl[4];
    #pragma unroll
    for (int ni = 0; ni < 4; ni++) bl[ni] = bias[bn + wn + ni * 16 + lm];

    #pragma unroll
    for (int mi = 0; mi < 8; mi++) {
        #pragma unroll
        for (int r = 0; r < 4; r++) {
            const int grow = bm + wm + mi * 16 + q4 * 4 + r;
            const float sc = xscale[grow];
            float* orow = out + (size_t)grow * N_DIM + bn + wn;
            #pragma unroll
            for (int ni = 0; ni < 4; ni++)
                orow[ni * 16 + lm] = sc * (float)acc[mi][ni][r] + bl[ni];
        }
    }
}

extern "C" void kernel_launch(void* const* d_in, const int* in_sizes, int n_in,
                              void* d_out, int out_size, void* d_ws, size_t ws_size,
                              hipStream_t stream) {
    const float* x    = (const float*)d_in[0];   // [4,2048,4096] = [8192,4096]
    const float* w    = (const float*)d_in[1];   // [4096,4096]
    const float* bias = (const float*)d_in[2];   // [4096]
    float* out = (float*)d_out;

    char* ws = (char*)d_ws;
    char*   xq       = ws;                                        // 32 MB
    char*   qw       = ws + (size_t)M_DIM * K_DIM;                // 16 MB
    float*  xscale   = (float*)(qw + (size_t)N_DIM * K_DIM);      // 32 KB
    double* partials = (double*)(xscale + M_DIM);                 // 8 KB
    float*  gamma_p  = (float*)(partials + 1024);                 // 4 B

    const int wn4 = (N_DIM * K_DIM) / 4;

    abssum_partial<<<1024, 256, 0, stream>>>((const float4*)w, partials);
    gamma_reduce<<<1, 256, 0, stream>>>(partials, gamma_p);
    wquant<<<(wn4 + 255) / 256, 256, 0, stream>>>((const float4*)w, (char4*)qw, gamma_p, wn4);
    xquant<<<M_DIM, 256, 0, stream>>>((const float4*)x, (char4*)xq, xscale);

    dim3 grid(N_DIM / BN, M_DIM / BM);   // (16, 32) = 512 blocks
    gemm_kernel<<<grid, 512, 0, stream>>>(xq, qw, xscale, bias, out);
}